// Round 1
// baseline (171.153 us; speedup 1.0000x reference)
//
#include <hip/hip_runtime.h>

#define EPS_F 1e-6f

__global__ __launch_bounds__(256) void mueller_kernel(
    const float* __restrict__ cos_theta_i,
    const float* __restrict__ eta_arr,
    float4* __restrict__ out, int n)
{
    int i = blockIdx.x * blockDim.x + threadIdx.x;
    if (i >= n) return;

    float ci   = cos_theta_i[i];
    float eta  = eta_arr[i];
    float rcp_eta = 1.0f / eta;
    bool  outside = (ci >= 0.0f);
    float eta_it = outside ? eta : rcp_eta;
    float eta_ti = outside ? rcp_eta : eta;

    float cts    = 1.0f - eta_ti * eta_ti * (1.0f - ci * ci);
    float ci_abs = fabsf(ci);

    // sqrtz: complex sqrt of (cts + EPS + 0j), then multiply by sign(cts>=0 ? +1 : -1)
    float x   = cts + EPS_F;
    float sgn = (cts >= 0.0f) ? 1.0f : -1.0f;
    float ctt_re, ctt_im;
    if (x >= 0.0f) { ctt_re = sqrtf(x) * sgn;  ctt_im = 0.0f; }
    else           { ctt_re = 0.0f;            ctt_im = sqrtf(-x) * sgn; }

    // a_s = (A - eta_it*ctt) / (A + eta_it*ctt), A = |ci|  (complex)
    float A    = ci_abs;
    float u_re = eta_it * ctt_re;
    float u_im = eta_it * ctt_im;
    float ds2  = (A + u_re) * (A + u_re) + u_im * u_im;
    float inv_ds = 1.0f / ds2;
    float as_re = (A * A - u_re * u_re - u_im * u_im) * inv_ds;
    float as_im = (-2.0f * A * u_im) * inv_ds;

    // a_p = (B - ctt) / (B + ctt), B = eta_it*|ci|  (complex)
    float B    = eta_it * ci_abs;
    float dp2  = (B + ctt_re) * (B + ctt_re) + ctt_im * ctt_im;
    float inv_dp = 1.0f / dp2;
    float ap_re = (B * B - ctt_re * ctt_re - ctt_im * ctt_im) * inv_dp;
    float ap_im = (-2.0f * B * ctt_im) * inv_dp;

    // bad = (eta==1) | (eta==0)  (dead for these inputs, kept for fidelity)
    if (eta == 1.0f || eta == 0.0f) {
        as_re = as_im = ap_re = ap_im = 0.0f;
    }

    float r_s  = as_re * as_re + as_im * as_im;
    float r_p  = ap_re * ap_re + ap_im * ap_im;
    float prod = r_p * r_s;

    // sincos of arg(a_p) - arg(a_s): value = a_p * conj(a_s) * 1/sqrt(prod+eps)
    float norm = (prod == 0.0f) ? 0.0f : 1.0f / sqrtf(prod + EPS_F);
    float cos_d = (ap_re * as_re + ap_im * as_im) * norm;
    float sin_d = (ap_im * as_re - ap_re * as_im) * norm;

    float a = 0.5f * (r_s + r_p);
    float b = 0.5f * (r_s - r_p);
    float c = sqrtf(prod + EPS_F);   // >= 1e-3, the c==0 guard is dead

    float cc = c * cos_d;
    float cs = c * sin_d;

    float4* o = out + (size_t)i * 4;
    o[0] = make_float4(a,    b,    0.0f, 0.0f);
    o[1] = make_float4(b,    a,    0.0f, 0.0f);
    o[2] = make_float4(0.0f, 0.0f, cc,   -cs);
    o[3] = make_float4(0.0f, 0.0f, cs,   cc);
}

extern "C" void kernel_launch(void* const* d_in, const int* in_sizes, int n_in,
                              void* d_out, int out_size, void* d_ws, size_t ws_size,
                              hipStream_t stream) {
    const float* ci  = (const float*)d_in[0];
    const float* eta = (const float*)d_in[1];
    float4* out = (float4*)d_out;
    int n = in_sizes[0];
    int block = 256;
    int grid = (n + block - 1) / block;
    mueller_kernel<<<grid, block, 0, stream>>>(ci, eta, out, n);
}